// Round 10
// baseline (1220.726 us; speedup 1.0000x reference)
//
#include <hip/hip_runtime.h>
#include <stdint.h>

typedef unsigned short ushort_t;
typedef __attribute__((ext_vector_type(8))) short bf8_t;     // 8 x bf16 (4 VGPRs)
typedef __attribute__((ext_vector_type(4))) float f4_t;      // MFMA accumulator
typedef __attribute__((ext_vector_type(4))) unsigned short us4_t;

#define TT 128

__device__ __forceinline__ ushort_t f2bf(float f) {
  uint32_t u = __builtin_bit_cast(uint32_t, f);
  u += 0x7fffu + ((u >> 16) & 1u);
  return (ushort_t)(u >> 16);
}
__device__ __forceinline__ float bf2f(ushort_t h) {
  uint32_t u = ((uint32_t)h) << 16;
  return __builtin_bit_cast(float, u);
}
__device__ __forceinline__ float sigm(float x) {
  return __builtin_amdgcn_rcpf(1.f + __expf(-x));
}
__device__ __forceinline__ float tanh_f(float x) {
  return 1.f - 2.f * __builtin_amdgcn_rcpf(1.f + __expf(2.f * x));
}

// ---- LLC-coherent (sc0 sc1) exchange primitives ----
__device__ __forceinline__ void x_store16(void* p, bf8_t v) {
  asm volatile("global_store_dwordx4 %0, %1, off sc0 sc1" :: "v"(p), "v"(v) : "memory");
}
__device__ __forceinline__ void x_store_flag(unsigned* p, unsigned v) {
  asm volatile("global_store_dword %0, %1, off sc0 sc1" :: "v"(p), "v"(v) : "memory");
}
__device__ __forceinline__ unsigned x_load_flag(const unsigned* p) {
  unsigned v;
  asm volatile("global_load_dword %0, %1, off sc0 sc1\n\ts_waitcnt vmcnt(0)"
               : "=v"(v) : "v"(p) : "memory");
  return v;
}
__device__ __forceinline__ void x_load4_issue(const void* p, bf8_t f[4]) {
  asm volatile(
      "global_load_dwordx4 %0, %4, off sc0 sc1\n\t"
      "global_load_dwordx4 %1, %4, off offset:1024 sc0 sc1\n\t"
      "global_load_dwordx4 %2, %4, off offset:2048 sc0 sc1\n\t"
      "global_load_dwordx4 %3, %4, off offset:3072 sc0 sc1"
      : "=&v"(f[0]), "=&v"(f[1]), "=&v"(f[2]), "=&v"(f[3]) : "v"(p) : "memory");
}

// ---------- pack kernels ----------
// Gate-interleaved: physical output col n = col*4 + gate.  WT[n][k] = W_{g=n&3}[k][j=n>>2]
__global__ void k_pack_w(const float* W0, const float* W1, const float* W2, const float* W3,
                         ushort_t* __restrict__ o) {
  int idx = blockIdx.x * 256 + threadIdx.x;   // 0..262143
  int n = idx >> 8, k = idx & 255;
  int g = n & 3, j = n >> 2;
  const float* Wg = g == 0 ? W0 : g == 1 ? W1 : g == 2 ? W2 : W3;
  o[(size_t)n * 256 + k] = f2bf(Wg[k * 256 + j]);
}

// U frag pack for 2-block pairs: UPJ2[((q*8+w)*8 + ktS)*4 + g][lane][e]
// ktS local (own k-half first): global kt = (ktS + 4*q) & 7.
// col = q*128 + w*16 + (lane&15); k = ktG*32 + (lane>>4)*8 + e; val = U_g[k][col]
__global__ void k_pack_u2(const float* U0, const float* U1, const float* U2, const float* U3,
                          ushort_t* __restrict__ o) {
  int idx = blockIdx.x * 256 + threadIdx.x;   // 0..32767
  int lane = idx & 63, g = (idx >> 6) & 3, ktS = (idx >> 8) & 7,
      w = (idx >> 11) & 7, q = (idx >> 14) & 1;
  const float* Ug = g == 0 ? U0 : g == 1 ? U1 : g == 2 ? U2 : U3;
  int ktG = (ktS + 4 * q) & 7;
  int col = q * 128 + w * 16 + (lane & 15);
  int kb = ktG * 32 + (lane >> 4) * 8;
#pragma unroll
  for (int e = 0; e < 8; ++e)
    o[(size_t)idx * 8 + e] = f2bf(Ug[(size_t)(kb + e) * 256 + col]);
}

// bias2[n] (n = j*4+g) = bW_g[j] + bU_g[j]   (folded into GEMM output)
__global__ void k_bias(const float* a0, const float* a1, const float* a2, const float* a3,
                       const float* b0, const float* b1, const float* b2, const float* b3,
                       float* __restrict__ o) {
  int n = blockIdx.x * 256 + threadIdx.x;  // 0..1023
  int g = n & 3, j = n >> 2;
  const float* pa = g == 0 ? a0 : g == 1 ? a1 : g == 2 ? a2 : a3;
  const float* pb = g == 0 ? b0 : g == 1 ? b1 : g == 2 ? b2 : b3;
  o[n] = pa[j] + pb[j];
}

// ---------- K1g: Pg[rr][1024] = emb[cap[rr]] @ W_all + bias ----------
__global__ __launch_bounds__(256) void k1g_gemm(const float* __restrict__ A,      // emb f32 [32000][256]
                                                const ushort_t* __restrict__ Bm,  // WT bf16 [1024][256]
                                                const float* __restrict__ bias,   // [1024]
                                                const int* __restrict__ cap,      // [65536]
                                                ushort_t* __restrict__ Pg) {      // [65536][1024]
  __shared__ ushort_t Al[128 * 32];
  __shared__ ushort_t Bl[128 * 32];
  const int tid = threadIdx.x;
  const int lane = tid & 63;
  const int w = tid >> 6;
  const int mt = blockIdx.x >> 3;
  const int nt = blockIdx.x & 7;
  const int m0 = mt * 128, n0 = nt * 128;
  const int qr = (w >> 1) * 64, qc = (w & 1) * 64;

  f4_t acc[4][4];
#pragma unroll
  for (int i = 0; i < 4; ++i)
#pragma unroll
    for (int j = 0; j < 4; ++j) acc[i][j] = f4_t{0.f, 0.f, 0.f, 0.f};

  const int r0 = tid >> 2, s0 = tid & 3;  // rows 0..63
  const int r1 = 64 + r0;                 // rows 64..127
  const int t0 = cap[m0 + r0];            // gathered A-row tokens
  const int t1 = cap[m0 + r1];

  for (int k0 = 0; k0 < 256; k0 += 32) {
    float4 a00 = *(const float4*)(A + (size_t)t0 * 256 + k0 + s0 * 8);
    float4 a01 = *(const float4*)(A + (size_t)t0 * 256 + k0 + s0 * 8 + 4);
    float4 a10 = *(const float4*)(A + (size_t)t1 * 256 + k0 + s0 * 8);
    float4 a11 = *(const float4*)(A + (size_t)t1 * 256 + k0 + s0 * 8 + 4);
    bf8_t b0 = *(const bf8_t*)(Bm + (size_t)(n0 + r0) * 256 + k0 + s0 * 8);
    bf8_t b1 = *(const bf8_t*)(Bm + (size_t)(n0 + r1) * 256 + k0 + s0 * 8);
    bf8_t pa0, pa1;
    pa0[0] = (short)f2bf(a00.x); pa0[1] = (short)f2bf(a00.y);
    pa0[2] = (short)f2bf(a00.z); pa0[3] = (short)f2bf(a00.w);
    pa0[4] = (short)f2bf(a01.x); pa0[5] = (short)f2bf(a01.y);
    pa0[6] = (short)f2bf(a01.z); pa0[7] = (short)f2bf(a01.w);
    pa1[0] = (short)f2bf(a10.x); pa1[1] = (short)f2bf(a10.y);
    pa1[2] = (short)f2bf(a10.z); pa1[3] = (short)f2bf(a10.w);
    pa1[4] = (short)f2bf(a11.x); pa1[5] = (short)f2bf(a11.y);
    pa1[6] = (short)f2bf(a11.z); pa1[7] = (short)f2bf(a11.w);
    __syncthreads();
    *(bf8_t*)(Al + (size_t)tid * 8) = pa0;
    *(bf8_t*)(Al + (size_t)(256 + tid) * 8) = pa1;
    *(bf8_t*)(Bl + (size_t)tid * 8) = b0;
    *(bf8_t*)(Bl + (size_t)(256 + tid) * 8) = b1;
    __syncthreads();
    bf8_t af[4], bfr[4];
#pragma unroll
    for (int i = 0; i < 4; ++i) {
      af[i]  = *(const bf8_t*)(Al + (qr + i * 16 + (lane & 15)) * 32 + (lane >> 4) * 8);
      bfr[i] = *(const bf8_t*)(Bl + (qc + i * 16 + (lane & 15)) * 32 + (lane >> 4) * 8);
    }
#pragma unroll
    for (int i = 0; i < 4; ++i)
#pragma unroll
      for (int j = 0; j < 4; ++j)
        acc[i][j] = __builtin_amdgcn_mfma_f32_16x16x32_bf16(af[i], bfr[j], acc[i][j], 0, 0, 0);
  }
#pragma unroll
  for (int i = 0; i < 4; ++i)
#pragma unroll
    for (int j = 0; j < 4; ++j)
#pragma unroll
      for (int r = 0; r < 4; ++r) {
        int row = m0 + qr + i * 16 + (lane >> 4) * 4 + r;
        int col = n0 + qc + j * 16 + (lane & 15);
        Pg[(size_t)row * 1024 + col] = f2bf(acc[i][j][r] + bias[col]);
      }
}

// ---------- K2: pair scan, 2 row-groups/pair — one exchange RT covers 32 rows ----------
// 16 pairs x 2 blocks (32 blocks); pair owns 32 batch rows (groups A=rows[0,16), B=[16,32)).
// Block q owns h cols [q*128,q*128+128) x 4 gates; U in regs. One flag per block-step.
#define OFFX(pp, G, par, qq) ((((((pp) * 2 + (G)) * 2 + (par)) * 2) + (qq)) * 4096)
__global__ __launch_bounds__(512, 2) void k_scan3(
    const ushort_t* __restrict__ Pg, const ushort_t* __restrict__ UPJ,
    float* __restrict__ hfin, char* __restrict__ pbuf, unsigned* __restrict__ flags) {
  __shared__ ushort_t hlds[2][2][2048];   // [group][parity]: 4KB each
  const int blk = blockIdx.x;
  const int pair = blk >> 1, q = blk & 1;
  const int tid = threadIdx.x, lane = tid & 63, w = tid >> 6;
  const int l15 = lane & 15, l16 = lane >> 4;
  const int jc = q * 128 + w * 16 + l15;
  const int rowA = pair * 32 + l16 * 4;
  const int rowB = rowA + 16;

  bf8_t u[8][4];
  {
    const ushort_t* ub = UPJ + (size_t)(q * 8 + w) * 32 * 512 + (size_t)lane * 8;
#pragma unroll
    for (int kt = 0; kt < 8; ++kt)
#pragma unroll
      for (int g = 0; g < 4; ++g)
        u[kt][g] = *(const bf8_t*)(ub + (kt * 4 + g) * 512);
  }

  const ushort_t* pgA[4];
  const ushort_t* pgB[4];
#pragma unroll
  for (int r = 0; r < 4; ++r) {
    pgA[r] = Pg + ((size_t)(rowA + r) * TT) * 1024 + jc * 4;
    pgB[r] = Pg + ((size_t)(rowB + r) * TT) * 1024 + jc * 4;
  }

  float cA[4] = {0.f, 0.f, 0.f, 0.f}, cB[4] = {0.f, 0.f, 0.f, 0.f};
  f4_t accA[4], accB[4];
#pragma unroll
  for (int g = 0; g < 4; ++g) { accA[g] = f4_t{0.f,0.f,0.f,0.f}; accB[g] = f4_t{0.f,0.f,0.f,0.f}; }

  // prologue: P-quads for step 0
  us4_t pfA[4], pfB[4];
#pragma unroll
  for (int r = 0; r < 4; ++r) {
    pfA[r] = *(const us4_t*)pgA[r]; pgA[r] += 1024;
    pfB[r] = *(const us4_t*)pgB[r]; pgB[r] += 1024;
  }

  const int wfrag = (w >> 1) * 4 + (w & 1) * 2 + (l15 >> 3);
  const int wbase = wfrag * 128 + l16 * 32 + (l15 & 7);
  const int cg = tid >> 8, ct = tid & 255;     // copy role: group + 16B slot
  unsigned* fown = flags + (pair * 2 + q) * TT;
  const unsigned* fpar = flags + (pair * 2 + (1 - q)) * TT;

#define GATES(cX, pfX, accX, hvX)                                        \
  _Pragma("unroll")                                                      \
  for (int r = 0; r < 4; ++r) {                                          \
    float pi = accX[0][r] + bf2f(pfX[r].x);                              \
    float pF = accX[1][r] + bf2f(pfX[r].y);                              \
    float po = accX[2][r] + bf2f(pfX[r].z);                              \
    float pg_ = accX[3][r] + bf2f(pfX[r].w);                             \
    float ig = sigm(pi), fg = sigm(pF), og = sigm(po), gg = tanh_f(pg_); \
    float cn = fmaf(fg, cX[r], ig * gg);                                 \
    cX[r] = cn;                                                          \
    hvX[r] = og * tanh_f(cn);                                            \
  }

  for (int t = 0; t < TT; ++t) {
    float hvA[4], hvB[4];
    GATES(cA, pfA, accA, hvA)
    GATES(cB, pfB, accB, hvB)
    if (t == TT - 1) {
#pragma unroll
      for (int r = 0; r < 4; ++r) {
        hfin[(size_t)(rowA + r) * 256 + jc] = hvA[r];
        hfin[(size_t)(rowB + r) * 256 + jc] = hvB[r];
      }
      break;
    }
    const int par = t & 1;
    // ---- h -> LDS (A-frag layout), both groups ----
#pragma unroll
    for (int r = 0; r < 4; ++r) {
      hlds[0][par][wbase + r * 8] = f2bf(hvA[r]);
      hlds[1][par][wbase + r * 8] = f2bf(hvB[r]);
    }
    __syncthreads();
    // ---- LDS -> LLC: all 512 threads (A: tid<256, B: tid>=256); per-lane drain ----
    {
      bf8_t v = *(const bf8_t*)(&hlds[cg][par][ct * 8]);
      x_store16(pbuf + OFFX(pair, cg, par, q) + ct * 16, v);
      asm volatile("s_waitcnt vmcnt(0)" ::: "memory");
    }
    __syncthreads();
    // ---- one flag covers both groups; tid0 poll with clean vmem queue ----
    if (tid == 0) {
      x_store_flag(fown + t, 1u);
      while (x_load_flag(fpar + t) == 0u) __builtin_amdgcn_s_sleep(1);
    }
    __syncthreads();
    // ---- MFMA for t+1: paf issues, Pg stream issues, own halves, counted waits ----
#pragma unroll
    for (int g = 0; g < 4; ++g) { accA[g] = f4_t{0.f,0.f,0.f,0.f}; accB[g] = f4_t{0.f,0.f,0.f,0.f}; }
    bf8_t pafA[4], pafB[4];
    x_load4_issue(pbuf + OFFX(pair, 0, par, 1 - q) + (l16 * 16 + l15) * 16, pafA);
    x_load4_issue(pbuf + OFFX(pair, 1, par, 1 - q) + (l16 * 16 + l15) * 16, pafB);
#pragma unroll
    for (int r = 0; r < 4; ++r) {
      pfA[r] = *(const us4_t*)pgA[r]; pgA[r] += 1024;
      pfB[r] = *(const us4_t*)pgB[r]; pgB[r] += 1024;
    }
#pragma unroll
    for (int kt = 0; kt < 4; ++kt) {
      bf8_t afk = *(const bf8_t*)(&hlds[0][par][((kt * 4 + l16) * 16 + l15) * 8]);
#pragma unroll
      for (int g = 0; g < 4; ++g)
        accA[g] = __builtin_amdgcn_mfma_f32_16x16x32_bf16(afk, u[kt][g], accA[g], 0, 0, 0);
    }
#pragma unroll
    for (int kt = 0; kt < 4; ++kt) {
      bf8_t bfk = *(const bf8_t*)(&hlds[1][par][((kt * 4 + l16) * 16 + l15) * 8]);
#pragma unroll
      for (int g = 0; g < 4; ++g)
        accB[g] = __builtin_amdgcn_mfma_f32_16x16x32_bf16(bfk, u[kt][g], accB[g], 0, 0, 0);
    }
    asm volatile("s_waitcnt vmcnt(12)" ::: "memory");  // pafA retired (8 pf + 4 pafB remain)
    __builtin_amdgcn_sched_barrier(0);
#pragma unroll
    for (int kt = 0; kt < 4; ++kt)
#pragma unroll
      for (int g = 0; g < 4; ++g)
        accA[g] = __builtin_amdgcn_mfma_f32_16x16x32_bf16(pafA[kt], u[4 + kt][g], accA[g], 0, 0, 0);
    asm volatile("s_waitcnt vmcnt(8)" ::: "memory");   // pafB retired (8 pf remain in flight)
    __builtin_amdgcn_sched_barrier(0);
#pragma unroll
    for (int kt = 0; kt < 4; ++kt)
#pragma unroll
      for (int g = 0; g < 4; ++g)
        accB[g] = __builtin_amdgcn_mfma_f32_16x16x32_bf16(pafB[kt], u[4 + kt][g], accB[g], 0, 0, 0);
  }
#undef GATES
}

// ---------- K3: out = normalize(h @ fc_w + fc_b) ----------
__global__ __launch_bounds__(256) void k3_fc(const float* __restrict__ hfin,
                                             const float* __restrict__ fcw,
                                             const float* __restrict__ fcb,
                                             float* __restrict__ out) {
  __shared__ float hrow[256];
  __shared__ float red[4];
  const int b = blockIdx.x, j = threadIdx.x;
  hrow[j] = hfin[(size_t)b * 256 + j];
  __syncthreads();
  float acc = fcb[j];
#pragma unroll 4
  for (int k = 0; k < 256; ++k) acc = fmaf(hrow[k], fcw[(size_t)k * 256 + j], acc);
  float ss = acc * acc;
#pragma unroll
  for (int o = 32; o > 0; o >>= 1) ss += __shfl_down(ss, o);
  if ((j & 63) == 0) red[j >> 6] = ss;
  __syncthreads();
  float tot = red[0] + red[1] + red[2] + red[3];
  float nrm = fmaxf(sqrtf(tot), 1e-12f);
  out[(size_t)b * 256 + j] = acc / nrm;
}

extern "C" void kernel_launch(void* const* d_in, const int* in_sizes, int n_in,
                              void* d_out, int out_size, void* d_ws, size_t ws_size,
                              hipStream_t stream) {
  const int* captions = (const int*)d_in[0];
  const float* emb = (const float*)d_in[1];
  const float *W[4], *bW[4], *U[4], *bU[4];
  for (int g = 0; g < 4; ++g) {
    W[g]  = (const float*)d_in[2 + 4 * g];
    bW[g] = (const float*)d_in[3 + 4 * g];
    U[g]  = (const float*)d_in[4 + 4 * g];
    bU[g] = (const float*)d_in[5 + 4 * g];
  }
  const float* fcw = (const float*)d_in[18];
  const float* fcb = (const float*)d_in[19];
  float* out = (float*)d_out;
  char* ws = (char*)d_ws;

  ushort_t* Pg    = (ushort_t*)(ws);                    // 65536*1024*2 = 134,217,728
  ushort_t* WT    = (ushort_t*)(ws + 134217728);        // 524,288
  ushort_t* UPJ2  = (ushort_t*)(ws + 134742016);        // 524,288
  float*    bias  = (float*)   (ws + 135266304);        // 4,096
  float*    hfin  = (float*)   (ws + 135270400);        // 524,288
  char*     pbuf  = (char*)    (ws + 135794688);        // 16*32768 = 524,288
  unsigned* flags = (unsigned*)(ws + 136318976);        // 32,768

  hipMemsetAsync(flags, 0, 32768, stream);
  k_pack_w<<<1024, 256, 0, stream>>>(W[0], W[1], W[2], W[3], WT);
  k_pack_u2<<<128, 256, 0, stream>>>(U[0], U[1], U[2], U[3], UPJ2);
  k_bias<<<4, 256, 0, stream>>>(bW[0], bW[1], bW[2], bW[3],
                                bU[0], bU[1], bU[2], bU[3], bias);
  k1g_gemm<<<4096, 256, 0, stream>>>(emb, WT, bias, captions, Pg);
  k_scan3<<<32, 512, 0, stream>>>(Pg, UPJ2, hfin, pbuf, flags);
  k3_fc<<<512, 256, 0, stream>>>(hfin, fcw, fcb, out);
}

// Round 11
// 441.422 us; speedup vs baseline: 2.7654x; 2.7654x over previous
//
#include <hip/hip_runtime.h>
#include <stdint.h>

typedef unsigned short ushort_t;
typedef __attribute__((ext_vector_type(8))) short bf8_t;     // 8 x bf16 (4 VGPRs)
typedef __attribute__((ext_vector_type(4))) float f4_t;      // MFMA accumulator
typedef __attribute__((ext_vector_type(4))) unsigned short us4_t;

#define TT 128

__device__ __forceinline__ ushort_t f2bf(float f) {
  uint32_t u = __builtin_bit_cast(uint32_t, f);
  u += 0x7fffu + ((u >> 16) & 1u);
  return (ushort_t)(u >> 16);
}
__device__ __forceinline__ float bf2f(ushort_t h) {
  uint32_t u = ((uint32_t)h) << 16;
  return __builtin_bit_cast(float, u);
}
__device__ __forceinline__ float sigm(float x) {
  return __builtin_amdgcn_rcpf(1.f + __expf(-x));
}
__device__ __forceinline__ float tanh_f(float x) {
  return 1.f - 2.f * __builtin_amdgcn_rcpf(1.f + __expf(2.f * x));
}

// ---- LLC-coherent (sc0 sc1) exchange primitives ----
__device__ __forceinline__ void x_store16(void* p, bf8_t v) {
  asm volatile("global_store_dwordx4 %0, %1, off sc0 sc1" :: "v"(p), "v"(v) : "memory");
}
__device__ __forceinline__ void x_store_flag_byte(void* p, unsigned v) {
  asm volatile("global_store_byte %0, %1, off sc0 sc1" :: "v"(p), "v"(v) : "memory");
}
__device__ __forceinline__ unsigned x_load_flag(const void* p) {
  unsigned v;
  asm volatile("global_load_dword %0, %1, off sc0 sc1\n\ts_waitcnt vmcnt(0)"
               : "=v"(v) : "v"(p) : "memory");
  return v;
}
__device__ __forceinline__ void x_load4_issue(const void* p, bf8_t f[4]) {
  asm volatile(
      "global_load_dwordx4 %0, %4, off sc0 sc1\n\t"
      "global_load_dwordx4 %1, %4, off offset:1024 sc0 sc1\n\t"
      "global_load_dwordx4 %2, %4, off offset:2048 sc0 sc1\n\t"
      "global_load_dwordx4 %3, %4, off offset:3072 sc0 sc1"
      : "=&v"(f[0]), "=&v"(f[1]), "=&v"(f[2]), "=&v"(f[3]) : "v"(p) : "memory");
}

// ---------- pack kernels ----------
// Gate-interleaved: physical output col n = col*4 + gate.  WT[n][k] = W_{g=n&3}[k][j=n>>2]
__global__ void k_pack_w(const float* W0, const float* W1, const float* W2, const float* W3,
                         ushort_t* __restrict__ o) {
  int idx = blockIdx.x * 256 + threadIdx.x;   // 0..262143
  int n = idx >> 8, k = idx & 255;
  int g = n & 3, j = n >> 2;
  const float* Wg = g == 0 ? W0 : g == 1 ? W1 : g == 2 ? W2 : W3;
  o[(size_t)n * 256 + k] = f2bf(Wg[k * 256 + j]);
}

// U frag pack for 2-block pairs: UPJ2[((q*8+w)*8 + ktS)*4 + g][lane][e]
// ktS local (own k-half first): global kt = (ktS + 4*q) & 7.
// col = q*128 + w*16 + (lane&15); k = ktG*32 + (lane>>4)*8 + e; val = U_g[k][col]
__global__ void k_pack_u2(const float* U0, const float* U1, const float* U2, const float* U3,
                          ushort_t* __restrict__ o) {
  int idx = blockIdx.x * 256 + threadIdx.x;   // 0..32767
  int lane = idx & 63, g = (idx >> 6) & 3, ktS = (idx >> 8) & 7,
      w = (idx >> 11) & 7, q = (idx >> 14) & 1;
  const float* Ug = g == 0 ? U0 : g == 1 ? U1 : g == 2 ? U2 : U3;
  int ktG = (ktS + 4 * q) & 7;
  int col = q * 128 + w * 16 + (lane & 15);
  int kb = ktG * 32 + (lane >> 4) * 8;
#pragma unroll
  for (int e = 0; e < 8; ++e)
    o[(size_t)idx * 8 + e] = f2bf(Ug[(size_t)(kb + e) * 256 + col]);
}

// bias2[n] (n = j*4+g) = bW_g[j] + bU_g[j]   (folded into GEMM output)
__global__ void k_bias(const float* a0, const float* a1, const float* a2, const float* a3,
                       const float* b0, const float* b1, const float* b2, const float* b3,
                       float* __restrict__ o) {
  int n = blockIdx.x * 256 + threadIdx.x;  // 0..1023
  int g = n & 3, j = n >> 2;
  const float* pa = g == 0 ? a0 : g == 1 ? a1 : g == 2 ? a2 : a3;
  const float* pb = g == 0 ? b0 : g == 1 ? b1 : g == 2 ? b2 : b3;
  o[n] = pa[j] + pb[j];
}

// ---------- K1g: Pg[rr][1024] = emb[cap[rr]] @ W_all + bias ----------
__global__ __launch_bounds__(256) void k1g_gemm(const float* __restrict__ A,      // emb f32 [32000][256]
                                                const ushort_t* __restrict__ Bm,  // WT bf16 [1024][256]
                                                const float* __restrict__ bias,   // [1024]
                                                const int* __restrict__ cap,      // [65536]
                                                ushort_t* __restrict__ Pg) {      // [65536][1024]
  __shared__ ushort_t Al[128 * 32];
  __shared__ ushort_t Bl[128 * 32];
  const int tid = threadIdx.x;
  const int lane = tid & 63;
  const int w = tid >> 6;
  const int mt = blockIdx.x >> 3;
  const int nt = blockIdx.x & 7;
  const int m0 = mt * 128, n0 = nt * 128;
  const int qr = (w >> 1) * 64, qc = (w & 1) * 64;

  f4_t acc[4][4];
#pragma unroll
  for (int i = 0; i < 4; ++i)
#pragma unroll
    for (int j = 0; j < 4; ++j) acc[i][j] = f4_t{0.f, 0.f, 0.f, 0.f};

  const int r0 = tid >> 2, s0 = tid & 3;  // rows 0..63
  const int r1 = 64 + r0;                 // rows 64..127
  const int t0 = cap[m0 + r0];            // gathered A-row tokens
  const int t1 = cap[m0 + r1];

  for (int k0 = 0; k0 < 256; k0 += 32) {
    float4 a00 = *(const float4*)(A + (size_t)t0 * 256 + k0 + s0 * 8);
    float4 a01 = *(const float4*)(A + (size_t)t0 * 256 + k0 + s0 * 8 + 4);
    float4 a10 = *(const float4*)(A + (size_t)t1 * 256 + k0 + s0 * 8);
    float4 a11 = *(const float4*)(A + (size_t)t1 * 256 + k0 + s0 * 8 + 4);
    bf8_t b0 = *(const bf8_t*)(Bm + (size_t)(n0 + r0) * 256 + k0 + s0 * 8);
    bf8_t b1 = *(const bf8_t*)(Bm + (size_t)(n0 + r1) * 256 + k0 + s0 * 8);
    bf8_t pa0, pa1;
    pa0[0] = (short)f2bf(a00.x); pa0[1] = (short)f2bf(a00.y);
    pa0[2] = (short)f2bf(a00.z); pa0[3] = (short)f2bf(a00.w);
    pa0[4] = (short)f2bf(a01.x); pa0[5] = (short)f2bf(a01.y);
    pa0[6] = (short)f2bf(a01.z); pa0[7] = (short)f2bf(a01.w);
    pa1[0] = (short)f2bf(a10.x); pa1[1] = (short)f2bf(a10.y);
    pa1[2] = (short)f2bf(a10.z); pa1[3] = (short)f2bf(a10.w);
    pa1[4] = (short)f2bf(a11.x); pa1[5] = (short)f2bf(a11.y);
    pa1[6] = (short)f2bf(a11.z); pa1[7] = (short)f2bf(a11.w);
    __syncthreads();
    *(bf8_t*)(Al + (size_t)tid * 8) = pa0;
    *(bf8_t*)(Al + (size_t)(256 + tid) * 8) = pa1;
    *(bf8_t*)(Bl + (size_t)tid * 8) = b0;
    *(bf8_t*)(Bl + (size_t)(256 + tid) * 8) = b1;
    __syncthreads();
    bf8_t af[4], bfr[4];
#pragma unroll
    for (int i = 0; i < 4; ++i) {
      af[i]  = *(const bf8_t*)(Al + (qr + i * 16 + (lane & 15)) * 32 + (lane >> 4) * 8);
      bfr[i] = *(const bf8_t*)(Bl + (qc + i * 16 + (lane & 15)) * 32 + (lane >> 4) * 8);
    }
#pragma unroll
    for (int i = 0; i < 4; ++i)
#pragma unroll
      for (int j = 0; j < 4; ++j)
        acc[i][j] = __builtin_amdgcn_mfma_f32_16x16x32_bf16(af[i], bfr[j], acc[i][j], 0, 0, 0);
  }
#pragma unroll
  for (int i = 0; i < 4; ++i)
#pragma unroll
    for (int j = 0; j < 4; ++j)
#pragma unroll
      for (int r = 0; r < 4; ++r) {
        int row = m0 + qr + i * 16 + (lane >> 4) * 4 + r;
        int col = n0 + qc + j * 16 + (lane & 15);
        Pg[(size_t)row * 1024 + col] = f2bf(acc[i][j][r] + bias[col]);
      }
}

// ---------- K2: pair scan (r9 geometry) with lean exchange protocol ----------
// 32 pairs x 2 blocks; pair owns 16 rows; block q owns cols [q*128,q*128+128) x 4 gates.
// Per step: GATES -> h->LDS -> ONE barrier -> waves0-3 copy+own-drain+byte-flag ->
// ALL waves poll flag-dword independently -> paf+Pg issue -> own MFMA -> vmcnt(4) ->
// partner MFMA. No post-poll barrier (double-buffered LDS makes 1 barrier/step safe).
__global__ __launch_bounds__(512, 2) void k_scan4(
    const ushort_t* __restrict__ Pg, const ushort_t* __restrict__ UPJ,
    float* __restrict__ hfin, char* __restrict__ pbuf, char* __restrict__ flags) {
  __shared__ ushort_t hlds[2][2048];
  const int blk = blockIdx.x;
  const int pair = blk >> 1, q = blk & 1;
  const int tid = threadIdx.x, lane = tid & 63, w = tid >> 6;
  const int l15 = lane & 15, l16 = lane >> 4;
  const int jc = q * 128 + w * 16 + l15;
  const int row0 = pair * 16 + l16 * 4;

  bf8_t u[8][4];
  {
    const ushort_t* ub = UPJ + (size_t)(q * 8 + w) * 32 * 512 + (size_t)lane * 8;
#pragma unroll
    for (int kt = 0; kt < 8; ++kt)
#pragma unroll
      for (int g = 0; g < 4; ++g)
        u[kt][g] = *(const bf8_t*)(ub + (kt * 4 + g) * 512);
  }

  // Pg stream pointers (advance 1024 ushorts = one step per issue)
  const ushort_t* pg[4];
#pragma unroll
  for (int r = 0; r < 4; ++r)
    pg[r] = Pg + ((size_t)(row0 + r) * TT) * 1024 + jc * 4;

  float c[4] = {0.f, 0.f, 0.f, 0.f};
  f4_t acc[4];
#pragma unroll
  for (int g = 0; g < 4; ++g) acc[g] = f4_t{0.f, 0.f, 0.f, 0.f};

  // prologue: P-quads for step 0
  us4_t pf[4];
#pragma unroll
  for (int r = 0; r < 4; ++r) { pf[r] = *(const us4_t*)pg[r]; pg[r] += 1024; }

  const int wfrag = (w >> 1) * 4 + (w & 1) * 2 + (l15 >> 3);
  const int wbase = wfrag * 128 + l16 * 32 + (l15 & 7);
  char* pairbuf = pbuf + (size_t)pair * 16384;
  char* fown = flags + (size_t)(pair * 2 + q) * TT * 4;
  const char* fpar = flags + (size_t)(pair * 2 + (1 - q)) * TT * 4;

  for (int t = 0; t < TT; ++t) {
    // ---- gates + cell update (4 cells: col jc, rows row0..row0+3) ----
    float hv[4];
#pragma unroll
    for (int r = 0; r < 4; ++r) {
      float pi = acc[0][r] + bf2f(pf[r].x);
      float pF = acc[1][r] + bf2f(pf[r].y);
      float po = acc[2][r] + bf2f(pf[r].z);
      float pg_ = acc[3][r] + bf2f(pf[r].w);
      float ig = sigm(pi), fg = sigm(pF), og = sigm(po), gg = tanh_f(pg_);
      float cn = fmaf(fg, c[r], ig * gg);
      c[r] = cn;
      hv[r] = og * tanh_f(cn);
    }
    if (t == TT - 1) {
#pragma unroll
      for (int r = 0; r < 4; ++r)
        hfin[(size_t)(row0 + r) * 256 + jc] = hv[r];
      break;
    }
    const int par = t & 1;
    // ---- h -> LDS (A-frag layout) ----
    {
      ushort_t* hb = &hlds[par][0];
#pragma unroll
      for (int r = 0; r < 4; ++r) hb[wbase + r * 8] = f2bf(hv[r]);
    }
    __syncthreads();                      // the ONLY barrier this step
    // ---- waves 0-3: copy 4KB to LLC, own-wave drain, lane0 byte-flag ----
    if (tid < 256) {
      bf8_t v = *(const bf8_t*)(&hlds[par][tid * 8]);
      x_store16(pairbuf + par * 8192 + q * 4096 + tid * 16, v);
      asm volatile("s_waitcnt vmcnt(0)" ::: "memory");
      if (lane == 0) x_store_flag_byte(fown + t * 4 + w, 1u);
    }
    // ---- all waves poll partner's flag dword independently (queue is clean) ----
    {
      unsigned fv = x_load_flag(fpar + t * 4);
      while (fv != 0x01010101u) {
        __builtin_amdgcn_s_sleep(1);
        fv = x_load_flag(fpar + t * 4);
      }
    }
    // ---- MFMA for t+1: paf issue, Pg stream issue, own half, vmcnt(4), partner ----
#pragma unroll
    for (int g = 0; g < 4; ++g) acc[g] = f4_t{0.f, 0.f, 0.f, 0.f};
    bf8_t paf[4];
    x_load4_issue(pairbuf + par * 8192 + (1 - q) * 4096 + (l16 * 16 + l15) * 16, paf);
#pragma unroll
    for (int r = 0; r < 4; ++r) { pf[r] = *(const us4_t*)pg[r]; pg[r] += 1024; }
#pragma unroll
    for (int kt = 0; kt < 4; ++kt) {
      bf8_t afk = *(const bf8_t*)(&hlds[par][((kt * 4 + l16) * 16 + l15) * 8]);
#pragma unroll
      for (int g = 0; g < 4; ++g)
        acc[g] = __builtin_amdgcn_mfma_f32_16x16x32_bf16(afk, u[kt][g], acc[g], 0, 0, 0);
    }
    asm volatile("s_waitcnt vmcnt(4)" ::: "memory");   // paf retired; pf stays in flight
    __builtin_amdgcn_sched_barrier(0);
#pragma unroll
    for (int kt = 0; kt < 4; ++kt)
#pragma unroll
      for (int g = 0; g < 4; ++g)
        acc[g] = __builtin_amdgcn_mfma_f32_16x16x32_bf16(paf[kt], u[4 + kt][g], acc[g], 0, 0, 0);
  }
}

// ---------- K3: out = normalize(h @ fc_w + fc_b) ----------
__global__ __launch_bounds__(256) void k3_fc(const float* __restrict__ hfin,
                                             const float* __restrict__ fcw,
                                             const float* __restrict__ fcb,
                                             float* __restrict__ out) {
  __shared__ float hrow[256];
  __shared__ float red[4];
  const int b = blockIdx.x, j = threadIdx.x;
  hrow[j] = hfin[(size_t)b * 256 + j];
  __syncthreads();
  float acc = fcb[j];
#pragma unroll 4
  for (int k = 0; k < 256; ++k) acc = fmaf(hrow[k], fcw[(size_t)k * 256 + j], acc);
  float ss = acc * acc;
#pragma unroll
  for (int o = 32; o > 0; o >>= 1) ss += __shfl_down(ss, o);
  if ((j & 63) == 0) red[j >> 6] = ss;
  __syncthreads();
  float tot = red[0] + red[1] + red[2] + red[3];
  float nrm = fmaxf(sqrtf(tot), 1e-12f);
  out[(size_t)b * 256 + j] = acc / nrm;
}

extern "C" void kernel_launch(void* const* d_in, const int* in_sizes, int n_in,
                              void* d_out, int out_size, void* d_ws, size_t ws_size,
                              hipStream_t stream) {
  const int* captions = (const int*)d_in[0];
  const float* emb = (const float*)d_in[1];
  const float *W[4], *bW[4], *U[4], *bU[4];
  for (int g = 0; g < 4; ++g) {
    W[g]  = (const float*)d_in[2 + 4 * g];
    bW[g] = (const float*)d_in[3 + 4 * g];
    U[g]  = (const float*)d_in[4 + 4 * g];
    bU[g] = (const float*)d_in[5 + 4 * g];
  }
  const float* fcw = (const float*)d_in[18];
  const float* fcb = (const float*)d_in[19];
  float* out = (float*)d_out;
  char* ws = (char*)d_ws;

  ushort_t* Pg    = (ushort_t*)(ws);                    // 65536*1024*2 = 134,217,728
  ushort_t* WT    = (ushort_t*)(ws + 134217728);        // 524,288
  ushort_t* UPJ2  = (ushort_t*)(ws + 134742016);        // 524,288
  float*    bias  = (float*)   (ws + 135266304);        // 4,096
  float*    hfin  = (float*)   (ws + 135270400);        // 524,288
  char*     pbuf  = (char*)    (ws + 135794688);        // 32*16384 = 524,288
  char*     flags = (char*)    (ws + 136318976);        // 64*128*4 = 32,768

  hipMemsetAsync(flags, 0, 32768, stream);
  k_pack_w<<<1024, 256, 0, stream>>>(W[0], W[1], W[2], W[3], WT);
  k_pack_u2<<<128, 256, 0, stream>>>(U[0], U[1], U[2], U[3], UPJ2);
  k_bias<<<4, 256, 0, stream>>>(bW[0], bW[1], bW[2], bW[3],
                                bU[0], bU[1], bU[2], bU[3], bias);
  k1g_gemm<<<4096, 256, 0, stream>>>(emb, WT, bias, captions, Pg);
  k_scan4<<<64, 512, 0, stream>>>(Pg, UPJ2, hfin, pbuf, flags);
  k3_fc<<<512, 256, 0, stream>>>(hfin, fcw, fcb, out);
}

// Round 12
// 414.498 us; speedup vs baseline: 2.9451x; 1.0650x over previous
//
#include <hip/hip_runtime.h>
#include <stdint.h>

typedef unsigned short ushort_t;
typedef __attribute__((ext_vector_type(8))) short bf8_t;     // 8 x bf16 (4 VGPRs)
typedef __attribute__((ext_vector_type(4))) float f4_t;      // MFMA accumulator
typedef __attribute__((ext_vector_type(4))) unsigned short us4_t;

#define TT 128

__device__ __forceinline__ ushort_t f2bf(float f) {
  uint32_t u = __builtin_bit_cast(uint32_t, f);
  u += 0x7fffu + ((u >> 16) & 1u);
  return (ushort_t)(u >> 16);
}
__device__ __forceinline__ float bf2f(ushort_t h) {
  uint32_t u = ((uint32_t)h) << 16;
  return __builtin_bit_cast(float, u);
}
__device__ __forceinline__ float sigm(float x) {
  return __builtin_amdgcn_rcpf(1.f + __expf(-x));
}
__device__ __forceinline__ float tanh_f(float x) {
  return 1.f - 2.f * __builtin_amdgcn_rcpf(1.f + __expf(2.f * x));
}

// ---- LLC-coherent (sc0 sc1) exchange primitives ----
__device__ __forceinline__ void x_store16(void* p, bf8_t v) {
  asm volatile("global_store_dwordx4 %0, %1, off sc0 sc1" :: "v"(p), "v"(v) : "memory");
}
__device__ __forceinline__ void x_store_flag_byte(void* p, unsigned v) {
  asm volatile("global_store_byte %0, %1, off sc0 sc1" :: "v"(p), "v"(v) : "memory");
}
__device__ __forceinline__ unsigned x_load_flag(const void* p) {
  unsigned v;
  asm volatile("global_load_dword %0, %1, off sc0 sc1\n\ts_waitcnt vmcnt(0)"
               : "=v"(v) : "v"(p) : "memory");
  return v;
}
__device__ __forceinline__ void x_load4_issue(const void* p, bf8_t f[4]) {
  asm volatile(
      "global_load_dwordx4 %0, %4, off sc0 sc1\n\t"
      "global_load_dwordx4 %1, %4, off offset:1024 sc0 sc1\n\t"
      "global_load_dwordx4 %2, %4, off offset:2048 sc0 sc1\n\t"
      "global_load_dwordx4 %3, %4, off offset:3072 sc0 sc1"
      : "=&v"(f[0]), "=&v"(f[1]), "=&v"(f[2]), "=&v"(f[3]) : "v"(p) : "memory");
}

// ---------- pack kernels ----------
// Gate-interleaved: physical output col n = col*4 + gate.  WT[n][k] = W_{g=n&3}[k][j=n>>2]
__global__ void k_pack_w(const float* W0, const float* W1, const float* W2, const float* W3,
                         ushort_t* __restrict__ o) {
  int idx = blockIdx.x * 256 + threadIdx.x;   // 0..262143
  int n = idx >> 8, k = idx & 255;
  int g = n & 3, j = n >> 2;
  const float* Wg = g == 0 ? W0 : g == 1 ? W1 : g == 2 ? W2 : W3;
  o[(size_t)n * 256 + k] = f2bf(Wg[k * 256 + j]);
}

// U frag pack for 2-block pairs: UPJ2[((q*8+w)*8 + ktS)*4 + g][lane][e]
// ktS local (own k-half first): global kt = (ktS + 4*q) & 7.
// col = q*128 + w*16 + (lane&15); k = ktG*32 + (lane>>4)*8 + e; val = U_g[k][col]
__global__ void k_pack_u2(const float* U0, const float* U1, const float* U2, const float* U3,
                          ushort_t* __restrict__ o) {
  int idx = blockIdx.x * 256 + threadIdx.x;   // 0..32767
  int lane = idx & 63, g = (idx >> 6) & 3, ktS = (idx >> 8) & 7,
      w = (idx >> 11) & 7, q = (idx >> 14) & 1;
  const float* Ug = g == 0 ? U0 : g == 1 ? U1 : g == 2 ? U2 : U3;
  int ktG = (ktS + 4 * q) & 7;
  int col = q * 128 + w * 16 + (lane & 15);
  int kb = ktG * 32 + (lane >> 4) * 8;
#pragma unroll
  for (int e = 0; e < 8; ++e)
    o[(size_t)idx * 8 + e] = f2bf(Ug[(size_t)(kb + e) * 256 + col]);
}

// bias2[n] (n = j*4+g) = bW_g[j] + bU_g[j]   (folded into GEMM output)
__global__ void k_bias(const float* a0, const float* a1, const float* a2, const float* a3,
                       const float* b0, const float* b1, const float* b2, const float* b3,
                       float* __restrict__ o) {
  int n = blockIdx.x * 256 + threadIdx.x;  // 0..1023
  int g = n & 3, j = n >> 2;
  const float* pa = g == 0 ? a0 : g == 1 ? a1 : g == 2 ? a2 : a3;
  const float* pb = g == 0 ? b0 : g == 1 ? b1 : g == 2 ? b2 : b3;
  o[n] = pa[j] + pb[j];
}

// ---------- K1: P = emb @ W_all + bias (vocab-wide, 17 GFLOP; bf16 MFMA) ----------
__global__ __launch_bounds__(256) void k1_gemm(const float* __restrict__ A,      // emb f32 [32000][256]
                                               const ushort_t* __restrict__ Bm,  // WT bf16 [1024][256]
                                               const float* __restrict__ bias,   // [1024]
                                               ushort_t* __restrict__ P) {       // [32000][1024]
  __shared__ ushort_t Al[128 * 32];
  __shared__ ushort_t Bl[128 * 32];
  const int tid = threadIdx.x;
  const int lane = tid & 63;
  const int w = tid >> 6;
  const int mt = blockIdx.x >> 3;
  const int nt = blockIdx.x & 7;
  const int m0 = mt * 128, n0 = nt * 128;
  const int qr = (w >> 1) * 64, qc = (w & 1) * 64;

  f4_t acc[4][4];
#pragma unroll
  for (int i = 0; i < 4; ++i)
#pragma unroll
    for (int j = 0; j < 4; ++j) acc[i][j] = f4_t{0.f, 0.f, 0.f, 0.f};

  const int r0 = tid >> 2, s0 = tid & 3;  // rows 0..63
  const int r1 = 64 + r0;                 // rows 64..127

  for (int k0 = 0; k0 < 256; k0 += 32) {
    float4 a00 = *(const float4*)(A + (size_t)(m0 + r0) * 256 + k0 + s0 * 8);
    float4 a01 = *(const float4*)(A + (size_t)(m0 + r0) * 256 + k0 + s0 * 8 + 4);
    float4 a10 = *(const float4*)(A + (size_t)(m0 + r1) * 256 + k0 + s0 * 8);
    float4 a11 = *(const float4*)(A + (size_t)(m0 + r1) * 256 + k0 + s0 * 8 + 4);
    bf8_t b0 = *(const bf8_t*)(Bm + (size_t)(n0 + r0) * 256 + k0 + s0 * 8);
    bf8_t b1 = *(const bf8_t*)(Bm + (size_t)(n0 + r1) * 256 + k0 + s0 * 8);
    bf8_t pa0, pa1;
    pa0[0] = (short)f2bf(a00.x); pa0[1] = (short)f2bf(a00.y);
    pa0[2] = (short)f2bf(a00.z); pa0[3] = (short)f2bf(a00.w);
    pa0[4] = (short)f2bf(a01.x); pa0[5] = (short)f2bf(a01.y);
    pa0[6] = (short)f2bf(a01.z); pa0[7] = (short)f2bf(a01.w);
    pa1[0] = (short)f2bf(a10.x); pa1[1] = (short)f2bf(a10.y);
    pa1[2] = (short)f2bf(a10.z); pa1[3] = (short)f2bf(a10.w);
    pa1[4] = (short)f2bf(a11.x); pa1[5] = (short)f2bf(a11.y);
    pa1[6] = (short)f2bf(a11.z); pa1[7] = (short)f2bf(a11.w);
    __syncthreads();
    *(bf8_t*)(Al + (size_t)tid * 8) = pa0;
    *(bf8_t*)(Al + (size_t)(256 + tid) * 8) = pa1;
    *(bf8_t*)(Bl + (size_t)tid * 8) = b0;
    *(bf8_t*)(Bl + (size_t)(256 + tid) * 8) = b1;
    __syncthreads();
    bf8_t af[4], bfr[4];
#pragma unroll
    for (int i = 0; i < 4; ++i) {
      af[i]  = *(const bf8_t*)(Al + (qr + i * 16 + (lane & 15)) * 32 + (lane >> 4) * 8);
      bfr[i] = *(const bf8_t*)(Bl + (qc + i * 16 + (lane & 15)) * 32 + (lane >> 4) * 8);
    }
#pragma unroll
    for (int i = 0; i < 4; ++i)
#pragma unroll
      for (int j = 0; j < 4; ++j)
        acc[i][j] = __builtin_amdgcn_mfma_f32_16x16x32_bf16(af[i], bfr[j], acc[i][j], 0, 0, 0);
  }
#pragma unroll
  for (int i = 0; i < 4; ++i)
#pragma unroll
    for (int j = 0; j < 4; ++j)
#pragma unroll
      for (int r = 0; r < 4; ++r) {
        int row = m0 + qr + i * 16 + (lane >> 4) * 4 + r;
        int col = n0 + qc + j * 16 + (lane & 15);
        P[(size_t)row * 1024 + col] = f2bf(acc[i][j][r] + bias[col]);
      }
}

// ---------- K2: pair scan (r11 protocol verbatim) + P-gather (tok 2 ahead) ----------
// 32 pairs x 2 blocks; pair owns 16 rows; block q owns cols [q*128,q*128+128) x 4 gates.
// Per step: GATES -> h->LDS -> ONE barrier -> waves0-3 copy+own-drain+byte-flag ->
// ALL waves poll flag-dword independently -> paf+pf-gather+tok issue -> own MFMA ->
// vmcnt(8) -> partner MFMA.
__global__ __launch_bounds__(512, 2) void k_scan5(
    const ushort_t* __restrict__ P, const ushort_t* __restrict__ UPJ,
    const int* __restrict__ cap, float* __restrict__ hfin,
    char* __restrict__ pbuf, char* __restrict__ flags) {
  __shared__ ushort_t hlds[2][2048];
  const int blk = blockIdx.x;
  const int pair = blk >> 1, q = blk & 1;
  const int tid = threadIdx.x, lane = tid & 63, w = tid >> 6;
  const int l15 = lane & 15, l16 = lane >> 4;
  const int jc = q * 128 + w * 16 + l15;
  const int row0 = pair * 16 + l16 * 4;

  bf8_t u[8][4];
  {
    const ushort_t* ub = UPJ + (size_t)(q * 8 + w) * 32 * 512 + (size_t)lane * 8;
#pragma unroll
    for (int kt = 0; kt < 8; ++kt)
#pragma unroll
      for (int g = 0; g < 4; ++g)
        u[kt][g] = *(const bf8_t*)(ub + (kt * 4 + g) * 512);
  }

  float c[4] = {0.f, 0.f, 0.f, 0.f};
  f4_t acc[4];
#pragma unroll
  for (int g = 0; g < 4; ++g) acc[g] = f4_t{0.f, 0.f, 0.f, 0.f};

  // prologue: pf = P-quads for step 0; tok = tokens for step 1
  int tok[4];
#pragma unroll
  for (int r = 0; r < 4; ++r) tok[r] = cap[(row0 + r) * TT];
  us4_t pf[4];
#pragma unroll
  for (int r = 0; r < 4; ++r)
    pf[r] = *(const us4_t*)(P + (size_t)tok[r] * 1024 + jc * 4);
#pragma unroll
  for (int r = 0; r < 4; ++r) tok[r] = cap[(row0 + r) * TT + 1];

  const int wfrag = (w >> 1) * 4 + (w & 1) * 2 + (l15 >> 3);
  const int wbase = wfrag * 128 + l16 * 32 + (l15 & 7);
  char* pairbuf = pbuf + (size_t)pair * 16384;
  char* fown = flags + (size_t)(pair * 2 + q) * TT * 4;
  const char* fpar = flags + (size_t)(pair * 2 + (1 - q)) * TT * 4;

  for (int t = 0; t < TT; ++t) {
    // ---- gates + cell update (4 cells: col jc, rows row0..row0+3) ----
    float hv[4];
#pragma unroll
    for (int r = 0; r < 4; ++r) {
      float pi = acc[0][r] + bf2f(pf[r].x);
      float pF = acc[1][r] + bf2f(pf[r].y);
      float po = acc[2][r] + bf2f(pf[r].z);
      float pg_ = acc[3][r] + bf2f(pf[r].w);
      float ig = sigm(pi), fg = sigm(pF), og = sigm(po), gg = tanh_f(pg_);
      float cn = fmaf(fg, c[r], ig * gg);
      c[r] = cn;
      hv[r] = og * tanh_f(cn);
    }
    if (t == TT - 1) {
#pragma unroll
      for (int r = 0; r < 4; ++r)
        hfin[(size_t)(row0 + r) * 256 + jc] = hv[r];
      break;
    }
    const int par = t & 1;
    // ---- h -> LDS (A-frag layout) ----
    {
      ushort_t* hb = &hlds[par][0];
#pragma unroll
      for (int r = 0; r < 4; ++r) hb[wbase + r * 8] = f2bf(hv[r]);
    }
    __syncthreads();                      // the ONLY barrier this step
    // ---- waves 0-3: copy 4KB to LLC, own-wave drain, lane0 byte-flag ----
    if (tid < 256) {
      bf8_t v = *(const bf8_t*)(&hlds[par][tid * 8]);
      x_store16(pairbuf + par * 8192 + q * 4096 + tid * 16, v);
      asm volatile("s_waitcnt vmcnt(0)" ::: "memory");
      if (lane == 0) x_store_flag_byte(fown + t * 4 + w, 1u);
    }
    // ---- all waves poll partner's flag dword independently (queue is clean) ----
    {
      unsigned fv = x_load_flag(fpar + t * 4);
      while (fv != 0x01010101u) {
        __builtin_amdgcn_s_sleep(1);
        fv = x_load_flag(fpar + t * 4);
      }
    }
    // ---- MFMA for t+1: paf issue, pf-gather (t+1 tokens), tok (t+2), own half,
    //      vmcnt(8) [paf retired; pf+tok in flight], partner half ----
#pragma unroll
    for (int g = 0; g < 4; ++g) acc[g] = f4_t{0.f, 0.f, 0.f, 0.f};
    bf8_t paf[4];
    x_load4_issue(pairbuf + par * 8192 + (1 - q) * 4096 + (l16 * 16 + l15) * 16, paf);
#pragma unroll
    for (int r = 0; r < 4; ++r)
      pf[r] = *(const us4_t*)(P + (size_t)tok[r] * 1024 + jc * 4);
    {
      const int t2 = (t + 2 < TT) ? t + 2 : TT - 1;
#pragma unroll
      for (int r = 0; r < 4; ++r) tok[r] = cap[(row0 + r) * TT + t2];
    }
#pragma unroll
    for (int kt = 0; kt < 4; ++kt) {
      bf8_t afk = *(const bf8_t*)(&hlds[par][((kt * 4 + l16) * 16 + l15) * 8]);
#pragma unroll
      for (int g = 0; g < 4; ++g)
        acc[g] = __builtin_amdgcn_mfma_f32_16x16x32_bf16(afk, u[kt][g], acc[g], 0, 0, 0);
    }
    asm volatile("s_waitcnt vmcnt(8)" ::: "memory");   // paf retired (pf+tok remain)
    __builtin_amdgcn_sched_barrier(0);
#pragma unroll
    for (int kt = 0; kt < 4; ++kt)
#pragma unroll
      for (int g = 0; g < 4; ++g)
        acc[g] = __builtin_amdgcn_mfma_f32_16x16x32_bf16(paf[kt], u[4 + kt][g], acc[g], 0, 0, 0);
  }
}

// ---------- K3: out = normalize(h @ fc_w + fc_b) ----------
__global__ __launch_bounds__(256) void k3_fc(const float* __restrict__ hfin,
                                             const float* __restrict__ fcw,
                                             const float* __restrict__ fcb,
                                             float* __restrict__ out) {
  __shared__ float hrow[256];
  __shared__ float red[4];
  const int b = blockIdx.x, j = threadIdx.x;
  hrow[j] = hfin[(size_t)b * 256 + j];
  __syncthreads();
  float acc = fcb[j];
#pragma unroll 4
  for (int k = 0; k < 256; ++k) acc = fmaf(hrow[k], fcw[(size_t)k * 256 + j], acc);
  float ss = acc * acc;
#pragma unroll
  for (int o = 32; o > 0; o >>= 1) ss += __shfl_down(ss, o);
  if ((j & 63) == 0) red[j >> 6] = ss;
  __syncthreads();
  float tot = red[0] + red[1] + red[2] + red[3];
  float nrm = fmaxf(sqrtf(tot), 1e-12f);
  out[(size_t)b * 256 + j] = acc / nrm;
}

extern "C" void kernel_launch(void* const* d_in, const int* in_sizes, int n_in,
                              void* d_out, int out_size, void* d_ws, size_t ws_size,
                              hipStream_t stream) {
  const int* captions = (const int*)d_in[0];
  const float* emb = (const float*)d_in[1];
  const float *W[4], *bW[4], *U[4], *bU[4];
  for (int g = 0; g < 4; ++g) {
    W[g]  = (const float*)d_in[2 + 4 * g];
    bW[g] = (const float*)d_in[3 + 4 * g];
    U[g]  = (const float*)d_in[4 + 4 * g];
    bU[g] = (const float*)d_in[5 + 4 * g];
  }
  const float* fcw = (const float*)d_in[18];
  const float* fcb = (const float*)d_in[19];
  float* out = (float*)d_out;
  char* ws = (char*)d_ws;

  ushort_t* P     = (ushort_t*)(ws);                    // 32000*1024*2 = 65,536,000
  ushort_t* WT    = (ushort_t*)(ws + 65536000);         // 524,288
  ushort_t* UPJ2  = (ushort_t*)(ws + 66060288);         // 524,288
  float*    bias  = (float*)   (ws + 66584576);         // 4,096
  float*    hfin  = (float*)   (ws + 66588672);         // 524,288
  char*     pbuf  = (char*)    (ws + 67112960);         // 32*16384 = 524,288
  char*     flags = (char*)    (ws + 67637248);         // 64*128*4 = 32,768

  hipMemsetAsync(flags, 0, 32768, stream);
  k_pack_w<<<1024, 256, 0, stream>>>(W[0], W[1], W[2], W[3], WT);
  k_pack_u2<<<128, 256, 0, stream>>>(U[0], U[1], U[2], U[3], UPJ2);
  k_bias<<<4, 256, 0, stream>>>(bW[0], bW[1], bW[2], bW[3],
                                bU[0], bU[1], bU[2], bU[3], bias);
  k1_gemm<<<2000, 256, 0, stream>>>(emb, WT, bias, P);
  k_scan5<<<64, 512, 0, stream>>>(P, UPJ2, captions, hfin, pbuf, flags);
  k3_fc<<<512, 256, 0, stream>>>(hfin, fcw, fcb, out);
}

// Round 14
// 412.611 us; speedup vs baseline: 2.9585x; 1.0046x over previous
//
#include <hip/hip_runtime.h>
#include <stdint.h>

typedef unsigned short ushort_t;
typedef __attribute__((ext_vector_type(8))) short bf8_t;     // 8 x bf16 (4 VGPRs)
typedef __attribute__((ext_vector_type(4))) float f4_t;      // MFMA accumulator
typedef __attribute__((ext_vector_type(4))) unsigned short us4_t;

#define TT 128

__device__ __forceinline__ ushort_t f2bf(float f) {
  uint32_t u = __builtin_bit_cast(uint32_t, f);
  u += 0x7fffu + ((u >> 16) & 1u);
  return (ushort_t)(u >> 16);
}
__device__ __forceinline__ float bf2f(ushort_t h) {
  uint32_t u = ((uint32_t)h) << 16;
  return __builtin_bit_cast(float, u);
}
__device__ __forceinline__ float sigm(float x) {
  return __builtin_amdgcn_rcpf(1.f + __expf(-x));
}
__device__ __forceinline__ float tanh_f(float x) {
  return 1.f - 2.f * __builtin_amdgcn_rcpf(1.f + __expf(2.f * x));
}

// ---- LLC-coherent (sc0 sc1) exchange primitives ----
__device__ __forceinline__ void x_store16(void* p, bf8_t v) {
  asm volatile("global_store_dwordx4 %0, %1, off sc0 sc1" :: "v"(p), "v"(v) : "memory");
}
__device__ __forceinline__ void x_store_flag_byte(void* p, unsigned v) {
  asm volatile("global_store_byte %0, %1, off sc0 sc1" :: "v"(p), "v"(v) : "memory");
}
__device__ __forceinline__ unsigned x_load_flag(const void* p) {
  unsigned v;
  asm volatile("global_load_dword %0, %1, off sc0 sc1\n\ts_waitcnt vmcnt(0)"
               : "=v"(v) : "v"(p) : "memory");
  return v;
}
__device__ __forceinline__ void x_load4_issue(const void* p, bf8_t f[4]) {
  asm volatile(
      "global_load_dwordx4 %0, %4, off sc0 sc1\n\t"
      "global_load_dwordx4 %1, %4, off offset:1024 sc0 sc1\n\t"
      "global_load_dwordx4 %2, %4, off offset:2048 sc0 sc1\n\t"
      "global_load_dwordx4 %3, %4, off offset:3072 sc0 sc1"
      : "=&v"(f[0]), "=&v"(f[1]), "=&v"(f[2]), "=&v"(f[3]) : "v"(p) : "memory");
}

// ---------- pack kernels ----------
// Gate-interleaved: physical output col n = col*4 + gate.  WT[n][k] = W_{g=n&3}[k][j=n>>2]
__global__ void k_pack_w(const float* W0, const float* W1, const float* W2, const float* W3,
                         ushort_t* __restrict__ o) {
  int idx = blockIdx.x * 256 + threadIdx.x;   // 0..262143
  int n = idx >> 8, k = idx & 255;
  int g = n & 3, j = n >> 2;
  const float* Wg = g == 0 ? W0 : g == 1 ? W1 : g == 2 ? W2 : W3;
  o[(size_t)n * 256 + k] = f2bf(Wg[k * 256 + j]);
}

// U frag pack for 2-block pairs: UPJ2[((q*8+w)*8 + ktS)*4 + g][lane][e]
// ktS local (own k-half first): global kt = (ktS + 4*q) & 7.
// col = q*128 + w*16 + (lane&15); k = ktG*32 + (lane>>4)*8 + e; val = U_g[k][col]
__global__ void k_pack_u2(const float* U0, const float* U1, const float* U2, const float* U3,
                          ushort_t* __restrict__ o) {
  int idx = blockIdx.x * 256 + threadIdx.x;   // 0..32767
  int lane = idx & 63, g = (idx >> 6) & 3, ktS = (idx >> 8) & 7,
      w = (idx >> 11) & 7, q = (idx >> 14) & 1;
  const float* Ug = g == 0 ? U0 : g == 1 ? U1 : g == 2 ? U2 : U3;
  int ktG = (ktS + 4 * q) & 7;
  int col = q * 128 + w * 16 + (lane & 15);
  int kb = ktG * 32 + (lane >> 4) * 8;
#pragma unroll
  for (int e = 0; e < 8; ++e)
    o[(size_t)idx * 8 + e] = f2bf(Ug[(size_t)(kb + e) * 256 + col]);
}

// bias2[n] (n = j*4+g) = bW_g[j] + bU_g[j]   (folded into GEMM output)
__global__ void k_bias(const float* a0, const float* a1, const float* a2, const float* a3,
                       const float* b0, const float* b1, const float* b2, const float* b3,
                       float* __restrict__ o) {
  int n = blockIdx.x * 256 + threadIdx.x;  // 0..1023
  int g = n & 3, j = n >> 2;
  const float* pa = g == 0 ? a0 : g == 1 ? a1 : g == 2 ? a2 : a3;
  const float* pb = g == 0 ? b0 : g == 1 ? b1 : g == 2 ? b2 : b3;
  o[n] = pa[j] + pb[j];
}

// ---------- K1: P = emb @ W_all + bias (vocab-wide, 17 GFLOP; bf16 MFMA) ----------
__global__ __launch_bounds__(256) void k1_gemm(const float* __restrict__ A,      // emb f32 [32000][256]
                                               const ushort_t* __restrict__ Bm,  // WT bf16 [1024][256]
                                               const float* __restrict__ bias,   // [1024]
                                               ushort_t* __restrict__ P) {       // [32000][1024]
  __shared__ ushort_t Al[128 * 32];
  __shared__ ushort_t Bl[128 * 32];
  const int tid = threadIdx.x;
  const int lane = tid & 63;
  const int w = tid >> 6;
  const int mt = blockIdx.x >> 3;
  const int nt = blockIdx.x & 7;
  const int m0 = mt * 128, n0 = nt * 128;
  const int qr = (w >> 1) * 64, qc = (w & 1) * 64;

  f4_t acc[4][4];
#pragma unroll
  for (int i = 0; i < 4; ++i)
#pragma unroll
    for (int j = 0; j < 4; ++j) acc[i][j] = f4_t{0.f, 0.f, 0.f, 0.f};

  const int r0 = tid >> 2, s0 = tid & 3;  // rows 0..63
  const int r1 = 64 + r0;                 // rows 64..127

  for (int k0 = 0; k0 < 256; k0 += 32) {
    float4 a00 = *(const float4*)(A + (size_t)(m0 + r0) * 256 + k0 + s0 * 8);
    float4 a01 = *(const float4*)(A + (size_t)(m0 + r0) * 256 + k0 + s0 * 8 + 4);
    float4 a10 = *(const float4*)(A + (size_t)(m0 + r1) * 256 + k0 + s0 * 8);
    float4 a11 = *(const float4*)(A + (size_t)(m0 + r1) * 256 + k0 + s0 * 8 + 4);
    bf8_t b0 = *(const bf8_t*)(Bm + (size_t)(n0 + r0) * 256 + k0 + s0 * 8);
    bf8_t b1 = *(const bf8_t*)(Bm + (size_t)(n0 + r1) * 256 + k0 + s0 * 8);
    bf8_t pa0, pa1;
    pa0[0] = (short)f2bf(a00.x); pa0[1] = (short)f2bf(a00.y);
    pa0[2] = (short)f2bf(a00.z); pa0[3] = (short)f2bf(a00.w);
    pa0[4] = (short)f2bf(a01.x); pa0[5] = (short)f2bf(a01.y);
    pa0[6] = (short)f2bf(a01.z); pa0[7] = (short)f2bf(a01.w);
    pa1[0] = (short)f2bf(a10.x); pa1[1] = (short)f2bf(a10.y);
    pa1[2] = (short)f2bf(a10.z); pa1[3] = (short)f2bf(a10.w);
    pa1[4] = (short)f2bf(a11.x); pa1[5] = (short)f2bf(a11.y);
    pa1[6] = (short)f2bf(a11.z); pa1[7] = (short)f2bf(a11.w);
    __syncthreads();
    *(bf8_t*)(Al + (size_t)tid * 8) = pa0;
    *(bf8_t*)(Al + (size_t)(256 + tid) * 8) = pa1;
    *(bf8_t*)(Bl + (size_t)tid * 8) = b0;
    *(bf8_t*)(Bl + (size_t)(256 + tid) * 8) = b1;
    __syncthreads();
    bf8_t af[4], bfr[4];
#pragma unroll
    for (int i = 0; i < 4; ++i) {
      af[i]  = *(const bf8_t*)(Al + (qr + i * 16 + (lane & 15)) * 32 + (lane >> 4) * 8);
      bfr[i] = *(const bf8_t*)(Bl + (qc + i * 16 + (lane & 15)) * 32 + (lane >> 4) * 8);
    }
#pragma unroll
    for (int i = 0; i < 4; ++i)
#pragma unroll
      for (int j = 0; j < 4; ++j)
        acc[i][j] = __builtin_amdgcn_mfma_f32_16x16x32_bf16(af[i], bfr[j], acc[i][j], 0, 0, 0);
  }
#pragma unroll
  for (int i = 0; i < 4; ++i)
#pragma unroll
    for (int j = 0; j < 4; ++j)
#pragma unroll
      for (int r = 0; r < 4; ++r) {
        int row = m0 + qr + i * 16 + (lane >> 4) * 4 + r;
        int col = n0 + qc + j * 16 + (lane & 15);
        P[(size_t)row * 1024 + col] = f2bf(acc[i][j][r] + bias[col]);
      }
}

// ---------- K2: pair scan (r11 protocol) + P-gather (tok 2 ahead) ----------
// 32 pairs x 2 blocks; pair owns 16 rows; block q owns cols [q*128,q*128+128) x 4 gates.
// Per step: GATES -> h->LDS -> ONE barrier -> waves0-3 copy+own-drain+byte-flag ->
// ALL waves poll flag-dword independently -> paf+pf-gather+tok issue -> own MFMA ->
// vmcnt(8) -> partner MFMA.
__global__ __launch_bounds__(512, 2) void k_scan5(
    const ushort_t* __restrict__ P, const ushort_t* __restrict__ UPJ,
    const int* __restrict__ cap, float* __restrict__ hfin,
    char* __restrict__ pbuf, char* __restrict__ flags) {
  __shared__ ushort_t hlds[2][2048];
  const int blk = blockIdx.x;
  const int pair = blk >> 1, q = blk & 1;
  const int tid = threadIdx.x, lane = tid & 63, w = tid >> 6;
  const int l15 = lane & 15, l16 = lane >> 4;
  const int jc = q * 128 + w * 16 + l15;
  const int row0 = pair * 16 + l16 * 4;

  bf8_t u[8][4];
  {
    const ushort_t* ub = UPJ + (size_t)(q * 8 + w) * 32 * 512 + (size_t)lane * 8;
#pragma unroll
    for (int kt = 0; kt < 8; ++kt)
#pragma unroll
      for (int g = 0; g < 4; ++g)
        u[kt][g] = *(const bf8_t*)(ub + (kt * 4 + g) * 512);
  }

  float c[4] = {0.f, 0.f, 0.f, 0.f};
  f4_t acc[4];
#pragma unroll
  for (int g = 0; g < 4; ++g) acc[g] = f4_t{0.f, 0.f, 0.f, 0.f};

  // prologue: pf = P-quads for step 0; tok = tokens for step 1
  int tok[4];
#pragma unroll
  for (int r = 0; r < 4; ++r) tok[r] = cap[(row0 + r) * TT];
  us4_t pf[4];
#pragma unroll
  for (int r = 0; r < 4; ++r)
    pf[r] = *(const us4_t*)(P + (size_t)tok[r] * 1024 + jc * 4);
#pragma unroll
  for (int r = 0; r < 4; ++r) tok[r] = cap[(row0 + r) * TT + 1];

  const int wfrag = (w >> 1) * 4 + (w & 1) * 2 + (l15 >> 3);
  const int wbase = wfrag * 128 + l16 * 32 + (l15 & 7);
  char* pairbuf = pbuf + (size_t)pair * 16384;
  char* fown = flags + (size_t)(pair * 2 + q) * TT * 4;
  const char* fpar = flags + (size_t)(pair * 2 + (1 - q)) * TT * 4;

  for (int t = 0; t < TT; ++t) {
    // ---- gates + cell update (4 cells: col jc, rows row0..row0+3) ----
    float hv[4];
#pragma unroll
    for (int r = 0; r < 4; ++r) {
      float pi = acc[0][r] + bf2f(pf[r].x);
      float pF = acc[1][r] + bf2f(pf[r].y);
      float po = acc[2][r] + bf2f(pf[r].z);
      float pg_ = acc[3][r] + bf2f(pf[r].w);
      float ig = sigm(pi), fg = sigm(pF), og = sigm(po), gg = tanh_f(pg_);
      float cn = fmaf(fg, c[r], ig * gg);
      c[r] = cn;
      hv[r] = og * tanh_f(cn);
    }
    if (t == TT - 1) {
#pragma unroll
      for (int r = 0; r < 4; ++r)
        hfin[(size_t)(row0 + r) * 256 + jc] = hv[r];
      break;
    }
    const int par = t & 1;
    // ---- h -> LDS (A-frag layout) ----
    {
      ushort_t* hb = &hlds[par][0];
#pragma unroll
      for (int r = 0; r < 4; ++r) hb[wbase + r * 8] = f2bf(hv[r]);
    }
    __syncthreads();                      // the ONLY barrier this step
    // ---- waves 0-3: copy 4KB to LLC, own-wave drain, lane0 byte-flag ----
    if (tid < 256) {
      bf8_t v = *(const bf8_t*)(&hlds[par][tid * 8]);
      x_store16(pairbuf + par * 8192 + q * 4096 + tid * 16, v);
      asm volatile("s_waitcnt vmcnt(0)" ::: "memory");
      if (lane == 0) x_store_flag_byte(fown + t * 4 + w, 1u);
    }
    // ---- all waves poll partner's flag dword independently (queue is clean) ----
    {
      unsigned fv = x_load_flag(fpar + t * 4);
      while (fv != 0x01010101u) {
        __builtin_amdgcn_s_sleep(1);
        fv = x_load_flag(fpar + t * 4);
      }
    }
    // ---- MFMA for t+1: paf issue, pf-gather (t+1 tokens), tok (t+2), own half,
    //      vmcnt(8) [paf retired; pf+tok in flight], partner half ----
#pragma unroll
    for (int g = 0; g < 4; ++g) acc[g] = f4_t{0.f, 0.f, 0.f, 0.f};
    bf8_t paf[4];
    x_load4_issue(pairbuf + par * 8192 + (1 - q) * 4096 + (l16 * 16 + l15) * 16, paf);
#pragma unroll
    for (int r = 0; r < 4; ++r)
      pf[r] = *(const us4_t*)(P + (size_t)tok[r] * 1024 + jc * 4);
    {
      const int t2 = (t + 2 < TT) ? t + 2 : TT - 1;
#pragma unroll
      for (int r = 0; r < 4; ++r) tok[r] = cap[(row0 + r) * TT + t2];
    }
#pragma unroll
    for (int kt = 0; kt < 4; ++kt) {
      bf8_t afk = *(const bf8_t*)(&hlds[par][((kt * 4 + l16) * 16 + l15) * 8]);
#pragma unroll
      for (int g = 0; g < 4; ++g)
        acc[g] = __builtin_amdgcn_mfma_f32_16x16x32_bf16(afk, u[kt][g], acc[g], 0, 0, 0);
    }
    asm volatile("s_waitcnt vmcnt(8)" ::: "memory");   // paf retired (pf+tok remain)
    __builtin_amdgcn_sched_barrier(0);
#pragma unroll
    for (int kt = 0; kt < 4; ++kt)
#pragma unroll
      for (int g = 0; g < 4; ++g)
        acc[g] = __builtin_amdgcn_mfma_f32_16x16x32_bf16(paf[kt], u[4 + kt][g], acc[g], 0, 0, 0);
  }
}

// ---------- K3: out = normalize(h @ fc_w + fc_b) ----------
__global__ __launch_bounds__(256) void k3_fc(const float* __restrict__ hfin,
                                             const float* __restrict__ fcw,
                                             const float* __restrict__ fcb,
                                             float* __restrict__ out) {
  __shared__ float hrow[256];
  __shared__ float red[4];
  const int b = blockIdx.x, j = threadIdx.x;
  hrow[j] = hfin[(size_t)b * 256 + j];
  __syncthreads();
  float acc = fcb[j];
#pragma unroll 4
  for (int k = 0; k < 256; ++k) acc = fmaf(hrow[k], fcw[(size_t)k * 256 + j], acc);
  float ss = acc * acc;
#pragma unroll
  for (int o = 32; o > 0; o >>= 1) ss += __shfl_down(ss, o);
  if ((j & 63) == 0) red[j >> 6] = ss;
  __syncthreads();
  float tot = red[0] + red[1] + red[2] + red[3];
  float nrm = fmaxf(sqrtf(tot), 1e-12f);
  out[(size_t)b * 256 + j] = acc / nrm;
}

extern "C" void kernel_launch(void* const* d_in, const int* in_sizes, int n_in,
                              void* d_out, int out_size, void* d_ws, size_t ws_size,
                              hipStream_t stream) {
  const int* captions = (const int*)d_in[0];
  const float* emb = (const float*)d_in[1];
  const float *W[4], *bW[4], *U[4], *bU[4];
  for (int g = 0; g < 4; ++g) {
    W[g]  = (const float*)d_in[2 + 4 * g];
    bW[g] = (const float*)d_in[3 + 4 * g];
    U[g]  = (const float*)d_in[4 + 4 * g];
    bU[g] = (const float*)d_in[5 + 4 * g];
  }
  const float* fcw = (const float*)d_in[18];
  const float* fcb = (const float*)d_in[19];
  float* out = (float*)d_out;
  char* ws = (char*)d_ws;

  ushort_t* P     = (ushort_t*)(ws);                    // 32000*1024*2 = 65,536,000
  ushort_t* WT    = (ushort_t*)(ws + 65536000);         // 524,288
  ushort_t* UPJ2  = (ushort_t*)(ws + 66060288);         // 524,288
  float*    bias  = (float*)   (ws + 66584576);         // 4,096
  float*    hfin  = (float*)   (ws + 66588672);         // 524,288
  char*     pbuf  = (char*)    (ws + 67112960);         // 32*16384 = 524,288
  char*     flags = (char*)    (ws + 67637248);         // 64*128*4 = 32,768

  hipMemsetAsync(flags, 0, 32768, stream);
  k_pack_w<<<1024, 256, 0, stream>>>(W[0], W[1], W[2], W[3], WT);
  k_pack_u2<<<128, 256, 0, stream>>>(U[0], U[1], U[2], U[3], UPJ2);
  k_bias<<<4, 256, 0, stream>>>(bW[0], bW[1], bW[2], bW[3],
                                bU[0], bU[1], bU[2], bU[3], bias);
  k1_gemm<<<2000, 256, 0, stream>>>(emb, WT, bias, P);
  k_scan5<<<64, 512, 0, stream>>>(P, UPJ2, captions, hfin, pbuf, flags);
  k3_fc<<<512, 256, 0, stream>>>(hfin, fcw, fcb, out);
}